// Round 6
// baseline (203.576 us; speedup 1.0000x reference)
//
#include <hip/hip_runtime.h>

#define SS 14
#define NUM_CLS 20
#define L_COORD 5.0f
#define L_NOOBJ 0.5f
#define CPB 256

// d_ws layout: float4 part[nblocks]

__global__ void __launch_bounds__(256) yolo_main(
    const float* __restrict__ pred,
    const float* __restrict__ tbox,
    const float* __restrict__ tcls,
    const int* __restrict__ mask,
    float4* __restrict__ part) {
  const int tid = threadIdx.x;
  const int c = blockIdx.x * CPB + tid;

  // ---- issue ALL loads up front, fully independent (deep ILP, no LDS, no barrier) ----
  const float2* p2 = (const float2*)(pred + (size_t)c * 30);  // byte offset 120c: 8-aligned ✓
  // box part: p0..p9
  float2 a0 = p2[0], a1 = p2[1], a2 = p2[2], a3 = p2[3], a4 = p2[4];
  float4 tb = ((const float4*)tbox)[c];
  int mi = mask[c];
  // cls part: pred[10..29]
  float2 b0 = p2[5], b1 = p2[6], b2 = p2[7], b3 = p2[8], b4 = p2[9];
  float2 b5 = p2[10], b6 = p2[11], b7 = p2[12], b8 = p2[13], b9 = p2[14];
  const float4* gc = (const float4*)(tcls + (size_t)c * 20);  // byte offset 80c: 16-aligned ✓
  float4 c0 = gc[0], c1 = gc[1], c2 = gc[2], c3 = gc[3], c4 = gc[4];

  float m = mi ? 1.0f : 0.0f;

  // ---- box terms (consume earliest loads first) ----
  float p0 = a0.x, p1 = a0.y, p2v = a1.x, p3 = a1.y, p4 = a2.x;
  float p5 = a2.y, p6 = a3.x, p7 = a3.y, p8 = a4.x, p9 = a4.y;

  float noobj_c = (1.0f - m) * (p4 * p4 + p9 * p9);

  const float invS = 1.0f / (float)SS;
  float gx0 = tb.x * invS - 0.5f * tb.z, gy0 = tb.y * invS - 0.5f * tb.w;
  float gx1 = tb.x * invS + 0.5f * tb.z, gy1 = tb.y * invS + 0.5f * tb.w;
  float ag = (gx1 - gx0) * (gy1 - gy0);

  float iou0, iou1;
  {
    float px0 = p0 * invS - 0.5f * p2v, py0 = p1 * invS - 0.5f * p3;
    float px1 = p0 * invS + 0.5f * p2v, py1 = p1 * invS + 0.5f * p3;
    float lx = fmaxf(px0, gx0), ly = fmaxf(py0, gy0);
    float rx = fminf(px1, gx1), ry = fminf(py1, gy1);
    float iw = fmaxf(rx - lx, 0.f), ih = fmaxf(ry - ly, 0.f);
    float inter = iw * ih;
    float ap = (px1 - px0) * (py1 - py0);
    iou0 = inter / (ap + ag - inter);
  }
  {
    float px0 = p5 * invS - 0.5f * p7, py0 = p6 * invS - 0.5f * p8;
    float px1 = p5 * invS + 0.5f * p7, py1 = p6 * invS + 0.5f * p8;
    float lx = fmaxf(px0, gx0), ly = fmaxf(py0, gy0);
    float rx = fminf(px1, gx1), ry = fminf(py1, gy1);
    float iw = fmaxf(rx - lx, 0.f), ih = fmaxf(ry - ly, 0.f);
    float inter = iw * ih;
    float ap = (px1 - px0) * (py1 - py0);
    iou1 = inter / (ap + ag - inter);
  }
  bool pick1 = (iou1 > iou0);  // jnp.argmax: first max wins ties
  float bx = pick1 ? p5 : p0;
  float by = pick1 ? p6 : p1;
  float bw = pick1 ? p7 : p2v;
  float bh = pick1 ? p8 : p3;
  float bc = pick1 ? p9 : p4;

  float dx = bx - tb.x, dy = by - tb.y;
  float dw = sqrtf(bw) - sqrtf(tb.z);
  float dh = sqrtf(bh) - sqrtf(tb.w);
  float reg_c = m * (dx * dx + dy * dy + dw * dw + dh * dh);
  float dc = bc - 1.0f;
  float con_c = m * dc * dc;

  // ---- cls loss (consume later loads) ----
  float s = 0.f;
  {
    float d;
    d = b0.x - c0.x; s += d * d;  d = b0.y - c0.y; s += d * d;
    d = b1.x - c0.z; s += d * d;  d = b1.y - c0.w; s += d * d;
    d = b2.x - c1.x; s += d * d;  d = b2.y - c1.y; s += d * d;
    d = b3.x - c1.z; s += d * d;  d = b3.y - c1.w; s += d * d;
    d = b4.x - c2.x; s += d * d;  d = b4.y - c2.y; s += d * d;
    d = b5.x - c2.z; s += d * d;  d = b5.y - c2.w; s += d * d;
    d = b6.x - c3.x; s += d * d;  d = b6.y - c3.y; s += d * d;
    d = b7.x - c3.z; s += d * d;  d = b7.y - c3.w; s += d * d;
    d = b8.x - c4.x; s += d * d;  d = b8.y - c4.y; s += d * d;
    d = b9.x - c4.z; s += d * d;  d = b9.y - c4.w; s += d * d;
  }
  float cls_c = s * m;

  // ---- reduction: wave shuffle -> LDS -> block partial ----
  float vx = cls_c, vy = noobj_c, vz = reg_c, vw = con_c;
  for (int off = 32; off >= 1; off >>= 1) {
    vx += __shfl_down(vx, off);
    vy += __shfl_down(vy, off);
    vz += __shfl_down(vz, off);
    vw += __shfl_down(vw, off);
  }
  __shared__ float4 red[4];
  int wid = tid >> 6;
  if ((tid & 63) == 0) red[wid] = make_float4(vx, vy, vz, vw);
  __syncthreads();
  if (tid == 0) {
    float4 t = red[0];
#pragma unroll
    for (int i = 1; i < 4; ++i) {
      t.x += red[i].x;
      t.y += red[i].y;
      t.z += red[i].z;
      t.w += red[i].w;
    }
    part[blockIdx.x] = t;
  }
}

__global__ void __launch_bounds__(256) yolo_reduce(
    const float4* __restrict__ part, float* __restrict__ out,
    int nblocks, float invN) {
  const int tid = threadIdx.x;
  float vx = 0.f, vy = 0.f, vz = 0.f, vw = 0.f;
  for (int i = tid; i < nblocks; i += 256) {
    float4 t = part[i];
    vx += t.x;
    vy += t.y;
    vz += t.z;
    vw += t.w;
  }
  for (int off = 32; off >= 1; off >>= 1) {
    vx += __shfl_down(vx, off);
    vy += __shfl_down(vy, off);
    vz += __shfl_down(vz, off);
    vw += __shfl_down(vw, off);
  }
  __shared__ float4 red[4];
  int wid = tid >> 6;
  if ((tid & 63) == 0) red[wid] = make_float4(vx, vy, vz, vw);
  __syncthreads();
  if (tid == 0) {
    float4 t = red[0];
#pragma unroll
    for (int i = 1; i < 4; ++i) {
      t.x += red[i].x;
      t.y += red[i].y;
      t.z += red[i].z;
      t.w += red[i].w;
    }
    float cls = t.x * invN;
    float noobj = L_NOOBJ * t.y * invN;
    float reg = L_COORD * t.z * invN;
    float con = t.w * invN;
    out[0] = reg + con + noobj + cls;
    out[1] = reg;
    out[2] = con;
    out[3] = noobj;
    out[4] = cls;
  }
}

extern "C" void kernel_launch(void* const* d_in, const int* in_sizes, int n_in,
                              void* d_out, int out_size, void* d_ws, size_t ws_size,
                              hipStream_t stream) {
  const float* pred = (const float*)d_in[0];
  const float* tbox = (const float*)d_in[1];
  const float* tcls = (const float*)d_in[2];
  const int* mask = (const int*)d_in[3];
  float* out = (float*)d_out;
  float4* part = (float4*)d_ws;

  int ncells = in_sizes[3];    // N*S*S = 802816, divisible by CPB
  int nblocks = ncells / CPB;  // 3136
  float invN = 1.0f / (float)(ncells / (SS * SS));

  yolo_main<<<nblocks, CPB, 0, stream>>>(pred, tbox, tcls, mask, part);
  yolo_reduce<<<1, 256, 0, stream>>>(part, out, nblocks, invN);
}